// Round 5
// baseline (833.912 us; speedup 1.0000x reference)
//
#include <hip/hip_runtime.h>
#include <hip/hip_bf16.h>

// DeepSeek MLA attention forward, MI355X.
// Round 7 (resubmit — round 4 bench was an infra failure, no kernel verdict):
// BK 32 -> 64 in gemm_bt (all four GEMM dispatches).
//  - halves barrier/vmcnt-drain count (the ~50% idle at MfmaUtil 17.8%),
//    doubles MFMA per barrier-pair (16 @ BN=64, 32 @ BN=128)
//  - K-tile stored as TWO 32-col panels (As[2]/Bs[2]): keeps the proven
//    64 B LDS row stride (no new bank conflicts) and the linear
//    global_load_lds destinations; only barrier cadence changes
//  - LDS 24 KB (BN=64) / 32 KB (BN=128): still >=4 blocks/CU
// attn (round-5, proven), fused qkv_a layout (round-6), converts/rms/prep
// unchanged.

typedef __attribute__((ext_vector_type(8))) __bf16 bf16x8;
typedef __attribute__((ext_vector_type(4))) __bf16 bf16x4;
typedef __attribute__((ext_vector_type(4))) float f32x4;

#define MFMA_BF16(a, b, c) __builtin_amdgcn_mfma_f32_16x16x32_bf16((a), (b), (c), 0, 0, 0)

__device__ __forceinline__ void async_load16(const void* g, void* l) {
  __builtin_amdgcn_global_load_lds(
      (const __attribute__((address_space(1))) void*)g,
      (__attribute__((address_space(3))) void*)l, 16, 0, 0);
}

// ---------------------------------------------------------------------------
// Dtype sniffer: votes 1 (bf16) / 0 (fp32) into flag[0].
// ---------------------------------------------------------------------------
__global__ void sniff_k(const unsigned int* __restrict__ u, int* __restrict__ flag) {
  int t = threadIdx.x;
  unsigned v = u[t];
  int e = (v >> 7) & 0xFF;
  int s = (e >= 96 && e <= 160) ? 1 : 0;
#pragma unroll
  for (int off = 32; off >= 1; off >>= 1) s += __shfl_xor(s, off);
  __shared__ int cnt[4];
  if ((t & 63) == 0) cnt[t >> 6] = s;
  __syncthreads();
  if (t == 0) flag[0] = (cnt[0] + cnt[1] + cnt[2] + cnt[3] >= 128) ? 1 : 0;
}

// Convert input (fp32 or bf16 per flag) to bf16. n must be a multiple of 4.
__global__ void convert_k(const void* __restrict__ in, __bf16* __restrict__ out,
                          long n, const int* __restrict__ flagp) {
  const int mode = *flagp;
  const long stride = (long)gridDim.x * blockDim.x;
  for (long t = blockIdx.x * (long)blockDim.x + threadIdx.x; t * 4 < n; t += stride) {
    long i = t * 4;
    if (mode) {
      *(uint2*)(out + i) = ((const uint2*)in)[t];
    } else {
      float4 v = ((const float4*)in)[t];
      out[i + 0] = (__bf16)v.x;
      out[i + 1] = (__bf16)v.y;
      out[i + 2] = (__bf16)v.z;
      out[i + 3] = (__bf16)v.w;
    }
  }
}

// ---------------------------------------------------------------------------
// GEMM: C[M,N] = A[M,K] @ B[N,K]^T (m97 structure, BK=64 as 2x32 panels).
// OUTMODE: 0 = fp32 out, 1 = bf16 out, 2 = runtime flag (1->bf16, 0->fp32).
// ---------------------------------------------------------------------------
template <int BN, int OUTMODE>
__global__ __launch_bounds__(256) void gemm_bt(
    const __bf16* __restrict__ A, const __bf16* __restrict__ B,
    void* __restrict__ Cv, const int* __restrict__ flagp,
    int M, int N, int K, int lda, int ldb, int ldc) {
  constexpr int BM = 128, BK = 64;
  constexpr int NT = (BN == 128) ? 4 : 2;
  constexpr int BCW = BN / 64;  // B chunks per wave per 32-col half
  __shared__ __align__(16) __bf16 As[2][BM * 32];
  __shared__ __align__(16) __bf16 Bs[2][BN * 32];
  const int tid = threadIdx.x;
  const int wave = tid >> 6, lane = tid & 63;
  const int m16 = lane & 15, quad = lane >> 4;
  const int m0 = blockIdx.y * BM, n0 = blockIdx.x * BN;
  const int wm = (wave >> 1) * 64;
  const int wn = (wave & 1) * (BN / 2);
  const int ar = lane >> 2;
  const int ak = (lane & 3) * 8;

  f32x4 acc[4][NT];
#pragma unroll
  for (int mt = 0; mt < 4; ++mt)
#pragma unroll
    for (int nt = 0; nt < NT; ++nt) acc[mt][nt] = (f32x4){0.f, 0.f, 0.f, 0.f};

  for (int k0 = 0; k0 < K; k0 += BK) {
#pragma unroll
    for (int h = 0; h < 2; ++h) {
#pragma unroll
      for (int c = 0; c < 2; ++c) {
        int q = wave * 2 + c;
        const __bf16* g = A + (size_t)(m0 + q * 16 + ar) * lda + k0 + h * 32 + ak;
        async_load16(g, (void*)(As[h] + q * 512));
      }
#pragma unroll
      for (int c = 0; c < BCW; ++c) {
        int q = wave * BCW + c;
        const __bf16* g = B + (size_t)(n0 + q * 16 + ar) * ldb + k0 + h * 32 + ak;
        async_load16(g, (void*)(Bs[h] + q * 512));
      }
    }
    __syncthreads();
#pragma unroll
    for (int h = 0; h < 2; ++h) {
      bf16x8 af[4], bfv[NT];
#pragma unroll
      for (int mt = 0; mt < 4; ++mt)
        af[mt] = *(const bf16x8*)&As[h][(wm + mt * 16 + m16) * 32 + quad * 8];
#pragma unroll
      for (int nt = 0; nt < NT; ++nt)
        bfv[nt] = *(const bf16x8*)&Bs[h][(wn + nt * 16 + m16) * 32 + quad * 8];
#pragma unroll
      for (int mt = 0; mt < 4; ++mt)
#pragma unroll
        for (int nt = 0; nt < NT; ++nt)
          acc[mt][nt] = MFMA_BF16(af[mt], bfv[nt], acc[mt][nt]);
    }
    __syncthreads();
  }
  bool obf16;
  if constexpr (OUTMODE == 2) obf16 = (*flagp != 0);
  else obf16 = (OUTMODE == 1);
#pragma unroll
  for (int mt = 0; mt < 4; ++mt)
#pragma unroll
    for (int nt = 0; nt < NT; ++nt)
#pragma unroll
      for (int rg = 0; rg < 4; ++rg) {
        size_t row = m0 + wm + mt * 16 + quad * 4 + rg;
        size_t col = n0 + wn + nt * 16 + m16;
        float v = acc[mt][nt][rg];
        if (obf16)
          ((__bf16*)Cv)[row * (size_t)ldc + col] = (__bf16)v;
        else
          ((float*)Cv)[row * (size_t)ldc + col] = v;
      }
}

// ---------------------------------------------------------------------------
// RMSNorm: fp32 in -> bf16 out, one block (256 thr) per row.
// ---------------------------------------------------------------------------
template <int COLS>
__global__ __launch_bounds__(256) void rms_k(const float* __restrict__ in, int ldin,
                                             const __bf16* __restrict__ w,
                                             __bf16* __restrict__ out, int ldout) {
  constexpr int PER = COLS / 256;
  const int row = blockIdx.x, tid = threadIdx.x;
  const float* x = in + (size_t)row * ldin;
  float v[PER];
  float ss = 0.f;
#pragma unroll
  for (int i = 0; i < PER; ++i) {
    v[i] = x[tid + i * 256];
    ss += v[i] * v[i];
  }
#pragma unroll
  for (int off = 32; off >= 1; off >>= 1) ss += __shfl_xor(ss, off);
  __shared__ float red[4];
  if ((tid & 63) == 0) red[tid >> 6] = ss;
  __syncthreads();
  ss = red[0] + red[1] + red[2] + red[3];
  float sc = rsqrtf(ss / (float)COLS + 1e-6f);
#pragma unroll
  for (int i = 0; i < PER; ++i)
    out[(size_t)row * ldout + tid + i * 256] =
        (__bf16)(v[i] * sc * (float)w[tid + i * 256]);
}

// ---------------------------------------------------------------------------
// Prep: build Q[bh][s][192], K[bh][s][192] with RoPE on last 64 dims.
// Q is pre-scaled by (1/sqrt(192))*log2(e) so attn softmax runs in exp2
// domain with no per-score multiply.
// ckv points at column 1536 of the fused [4096][2112] fp32 projection buffer
// (row stride 2112); k_pe RoPE input is its columns 512..575 (pre-norm).
// ---------------------------------------------------------------------------
#define QK_SCALE (0.07216878364870323f * 1.4426950408889634f)

__global__ void prep_k(const __bf16* __restrict__ qb,    // [4096][3072]
                       const float* __restrict__ ckv,    // [4096][*] fp32, ld=2112
                       const __bf16* __restrict__ kvb,   // [4096][4096]
                       const __bf16* __restrict__ cosp,  // [2048][64] bf16
                       const __bf16* __restrict__ sinp,
                       __bf16* __restrict__ Qg, __bf16* __restrict__ Kg) {
  const int bs = blockIdx.x;  // b*2048 + s
  const int s = bs & 2047, b = bs >> 11;
  const int d = threadIdx.x;  // 0..191
  float c = 0.f, sn = 0.f, kpe = 0.f;
  if (d >= 128) {
    int i = d - 128;
    c = (float)cosp[s * 64 + i];
    sn = (float)sinp[s * 64 + i];
    const float* ck = ckv + (size_t)bs * 2112 + 512;
    if (i < 32)
      kpe = ck[2 * i] * c - ck[2 * i + 1] * sn;
    else {
      int j = i - 32;
      kpe = ck[2 * j + 1] * c + ck[2 * j] * sn;
    }
  }
  for (int h = 0; h < 16; ++h) {
    size_t orow = ((size_t)(b * 16 + h) * 2048 + s) * 192 + d;
    const __bf16* qr = qb + (size_t)bs * 3072 + h * 192;
    float qv;
    if (d < 128)
      qv = (float)qr[d];
    else {
      int i = d - 128;
      if (i < 32)
        qv = (float)qr[128 + 2 * i] * c - (float)qr[128 + 2 * i + 1] * sn;
      else {
        int j = i - 32;
        qv = (float)qr[128 + 2 * j + 1] * c + (float)qr[128 + 2 * j] * sn;
      }
    }
    Qg[orow] = (__bf16)(qv * QK_SCALE);
    float kval = (d < 128) ? (float)kvb[(size_t)bs * 4096 + h * 256 + d] : kpe;
    Kg[orow] = (__bf16)kval;
  }
}

// ---------------------------------------------------------------------------
// Causal flash attention, round-5 structure (unchanged).
// 64 q-rows per block (16 per wave), 1024 blocks. LDS 52 KB -> 3 blocks/CU.
// XCD-affine bh map, longest-first q-tiles, reg-prefetched K/V staging,
// exp2-domain softmax, diagonal-only mask, defer-rescale (THR=8).
// launch_bounds(256,2): (256,3) forced 84 VGPR -> spills -> 1.2 GB scratch.
// ---------------------------------------------------------------------------
__global__ __launch_bounds__(256, 2) void attn_k(const __bf16* __restrict__ Qg,
                                                 const __bf16* __restrict__ Kg,
                                                 const __bf16* __restrict__ kvb,
                                                 __bf16* __restrict__ Og) {
  constexpr int S = 2048;
  __shared__ __align__(16) __bf16 Ks[64 * 200];   // 25.6 KB
  __shared__ __align__(16) __bf16 Vt[128 * 72];   // 18.4 KB
  __shared__ __align__(16) __bf16 Ps[64 * 72];    //  9.2 KB
  // work mapping: L in [0,1024). xcd class = L&7; heavy xt first.
  const int L = blockIdx.x + (blockIdx.y << 5);
  const int xcd = L & 7, m = L >> 3;
  const int xt = 31 - (m >> 2);          // q-tile 31..0, longest first
  const int bh = ((m & 3) << 3) | xcd;   // bh&7 == L&7
  const int b = bh >> 4, h = bh & 15;
  const int i0 = xt * 64;
  const int tid = threadIdx.x, wave = tid >> 6, lane = tid & 63;
  const int m16 = lane & 15, quad = lane >> 4;
  // V-transpose thread mapping: 4 s-rows x 8 d-cols per thread
  const int sb = (tid & 15) * 4, d0 = (tid >> 4) * 8;

  // Q fragments resident in registers (16 q-rows per wave)
  bf16x8 qf[6];
  const __bf16* Qb = Qg + ((size_t)bh * S + i0 + wave * 16) * 192;
#pragma unroll
  for (int kc = 0; kc < 6; ++kc)
    qf[kc] = *(const bf16x8*)(Qb + m16 * 192 + kc * 32 + quad * 8);

  f32x4 oacc[8];
#pragma unroll
  for (int nt = 0; nt < 8; ++nt) oacc[nt] = (f32x4){0.f, 0.f, 0.f, 0.f};
  float mrow[4], lrow[4];
#pragma unroll
  for (int rg = 0; rg < 4; ++rg) {
    mrow[rg] = -1e30f;
    lrow[rg] = 0.f;
  }

  const __bf16* Kbase = Kg + (size_t)bh * S * 192;
  const __bf16* Vbase = kvb + (size_t)b * S * 4096 + h * 256 + 128 + d0;
  const int ntl = xt + 1;

  // K staging geometry: 1536 chunks of 8 = 64 rows x 24 chunks
  int krow[6], kcol[6];
#pragma unroll
  for (int c = 0; c < 6; ++c) {
    int chunk = tid + c * 256;
    krow[c] = chunk / 24;
    kcol[c] = (chunk % 24) * 8;
  }

  // prefetch tile 0
  bf16x8 kr[6], vr[4];
#pragma unroll
  for (int c = 0; c < 6; ++c)
    kr[c] = *(const bf16x8*)(Kbase + (size_t)krow[c] * 192 + kcol[c]);
#pragma unroll
  for (int r = 0; r < 4; ++r)
    vr[r] = *(const bf16x8*)(Vbase + (size_t)(sb + r) * 4096);

  for (int t = 0; t < ntl; ++t) {
    const int kt0 = t * 64;
    __syncthreads();  // B1: prev compute done; also drains prefetched loads
    // regs -> LDS
#pragma unroll
    for (int c = 0; c < 6; ++c)
      *(bf16x8*)&Ks[krow[c] * 200 + kcol[c]] = kr[c];
#pragma unroll
    for (int j = 0; j < 8; ++j) {
      bf16x4 wv = {vr[0][j], vr[1][j], vr[2][j], vr[3][j]};
      *(bf16x4*)&Vt[(d0 + j) * 72 + sb] = wv;
    }
    __syncthreads();  // B2: LDS visible (no vmem in flight here)
    // prefetch tile t+1 — stays in flight across the whole compute phase
    if (t + 1 < ntl) {
      const __bf16* Kb = Kbase + (size_t)(kt0 + 64) * 192;
#pragma unroll
      for (int c = 0; c < 6; ++c)
        kr[c] = *(const bf16x8*)(Kb + (size_t)krow[c] * 192 + kcol[c]);
      const __bf16* Vb = Vbase + (size_t)(kt0 + 64) * 4096;
#pragma unroll
      for (int r = 0; r < 4; ++r)
        vr[r] = *(const bf16x8*)(Vb + (size_t)(sb + r) * 4096);
    }

    // S = Q K^T  (already scaled: Qg carries scale*log2e)
    f32x4 sacc[4];
#pragma unroll
    for (int nt = 0; nt < 4; ++nt) sacc[nt] = (f32x4){0.f, 0.f, 0.f, 0.f};
#pragma unroll
    for (int kc = 0; kc < 6; ++kc) {
      bf16x8 bv[4];
#pragma unroll
      for (int nt = 0; nt < 4; ++nt)
        bv[nt] = *(const bf16x8*)&Ks[(nt * 16 + m16) * 200 + kc * 32 + quad * 8];
#pragma unroll
      for (int nt = 0; nt < 4; ++nt)
        sacc[nt] = MFMA_BF16(qf[kc], bv[nt], sacc[nt]);
    }
    // causal mask — only the diagonal tile can mask (kt0 == i0 there)
    if (t == ntl - 1) {
#pragma unroll
      for (int nt = 0; nt < 4; ++nt)
#pragma unroll
        for (int rg = 0; rg < 4; ++rg) {
          int qrow = wave * 16 + quad * 4 + rg;  // local row
          int kcl = nt * 16 + m16;               // local col
          if (kcl > qrow) sacc[nt][rg] = -1e30f;
        }
    }
    // online softmax (exp2 domain)
    float tm[4];
#pragma unroll
    for (int rg = 0; rg < 4; ++rg) {
      float v = fmaxf(fmaxf(sacc[0][rg], sacc[1][rg]),
                      fmaxf(sacc[2][rg], sacc[3][rg]));
      v = fmaxf(v, __shfl_xor(v, 1));
      v = fmaxf(v, __shfl_xor(v, 2));
      v = fmaxf(v, __shfl_xor(v, 4));
      v = fmaxf(v, __shfl_xor(v, 8));
      tm[rg] = v;
    }
    bool nomax = true;
#pragma unroll
    for (int rg = 0; rg < 4; ++rg) nomax = nomax && (tm[rg] <= mrow[rg] + 8.f);
    if (__all(nomax)) {
      // deferred path: keep stale max (p bounded by 2^8), no O-rescale
#pragma unroll
      for (int rg = 0; rg < 4; ++rg) {
        float rs = 0.f;
#pragma unroll
        for (int nt = 0; nt < 4; ++nt) {
          float p = exp2f(sacc[nt][rg] - mrow[rg]);
          sacc[nt][rg] = p;
          rs += p;
        }
        rs += __shfl_xor(rs, 1);
        rs += __shfl_xor(rs, 2);
        rs += __shfl_xor(rs, 4);
        rs += __shfl_xor(rs, 8);
        lrow[rg] += rs;
      }
    } else {
#pragma unroll
      for (int rg = 0; rg < 4; ++rg) {
        float nm = fmaxf(mrow[rg], tm[rg]);
        float alpha = exp2f(mrow[rg] - nm);
        mrow[rg] = nm;
        float rs = 0.f;
#pragma unroll
        for (int nt = 0; nt < 4; ++nt) {
          float p = exp2f(sacc[nt][rg] - nm);
          sacc[nt][rg] = p;
          rs += p;
        }
        rs += __shfl_xor(rs, 1);
        rs += __shfl_xor(rs, 2);
        rs += __shfl_xor(rs, 4);
        rs += __shfl_xor(rs, 8);
        lrow[rg] = lrow[rg] * alpha + rs;
#pragma unroll
        for (int nt = 0; nt < 8; ++nt) oacc[nt][rg] *= alpha;
      }
    }
    // P -> LDS (wave-private rows, no barrier needed)
#pragma unroll
    for (int nt = 0; nt < 4; ++nt)
#pragma unroll
      for (int rg = 0; rg < 4; ++rg)
        Ps[(wave * 16 + quad * 4 + rg) * 72 + nt * 16 + m16] =
            (__bf16)sacc[nt][rg];
    // O += P V
#pragma unroll
    for (int kc2 = 0; kc2 < 2; ++kc2) {
      bf16x8 af = *(const bf16x8*)&Ps[(wave * 16 + m16) * 72 + kc2 * 32 + quad * 8];
#pragma unroll
      for (int nt = 0; nt < 8; ++nt) {
        bf16x8 bv = *(const bf16x8*)&Vt[(nt * 16 + m16) * 72 + kc2 * 32 + quad * 8];
        oacc[nt] = MFMA_BF16(af, bv, oacc[nt]);
      }
    }
  }
  // epilogue
#pragma unroll
  for (int nt = 0; nt < 8; ++nt)
#pragma unroll
    for (int rg = 0; rg < 4; ++rg) {
      int sg = i0 + wave * 16 + quad * 4 + rg;
      int d = nt * 16 + m16;
      float val = oacc[nt][rg] / lrow[rg];
      Og[((size_t)b * S + sg) * 2048 + h * 128 + d] = (__bf16)val;
    }
}

// ---------------------------------------------------------------------------
extern "C" void kernel_launch(void* const* d_in, const int* in_sizes, int n_in,
                              void* d_out, int out_size, void* d_ws, size_t ws_size,
                              hipStream_t stream) {
  char* w0 = (char*)d_ws;
  int* flag = (int*)w0;
  char* w = w0 + 256;
  __bf16* hid_bf = (__bf16*)w;   w += (size_t)4096 * 5120 * 2;
  // wqa_bf and wkva_bf adjacent -> contiguous fused weight [2112][5120]
  __bf16* wqa_bf = (__bf16*)w;   w += (size_t)1536 * 5120 * 2;
  __bf16* wkva_bf = (__bf16*)w;  w += (size_t)576 * 5120 * 2;
  __bf16* wqb_bf = (__bf16*)w;   w += (size_t)3072 * 1536 * 2;
  __bf16* wkvb_bf = (__bf16*)w;  w += (size_t)4096 * 512 * 2;
  __bf16* wo_bf = (__bf16*)w;    w += (size_t)5120 * 2048 * 2;
  __bf16* cos_bf = (__bf16*)w;   w += (size_t)2048 * 64 * 2;
  __bf16* sin_bf = (__bf16*)w;   w += (size_t)2048 * 64 * 2;
  __bf16* qln_bf = (__bf16*)w;   w += 4096;
  __bf16* kvln_bf = (__bf16*)w;  w += 4096;
  float* qkv = (float*)w;        w += (size_t)4096 * 2112 * 4;  // [q_a(1536)|ckv(576)]
  __bf16* qan = (__bf16*)w;      w += (size_t)4096 * 1536 * 2;
  __bf16* qb = (__bf16*)w;       w += (size_t)4096 * 3072 * 2;
  __bf16* ckvn = (__bf16*)w;     w += (size_t)4096 * 512 * 2;
  __bf16* kvb = (__bf16*)w;      w += (size_t)4096 * 4096 * 2;
  // Overlays: Qg over hid_bf (dead after fused qkv_a gemm); Kg over
  // wqa_bf+wkva_bf+wqb_bf (all dead before prep_k); ao over qkv (dead after
  // rms + prep_k, attn writes it afterwards).
  __bf16* Qg = hid_bf;
  __bf16* Kg = wqa_bf;
  __bf16* ao = (__bf16*)qkv;

  sniff_k<<<1, 256, 0, stream>>>((const unsigned int*)d_in[0], flag);
  convert_k<<<1024, 256, 0, stream>>>(d_in[0], hid_bf, (long)4096 * 5120, flag);
  convert_k<<<1024, 256, 0, stream>>>(d_in[3], wqa_bf, (long)1536 * 5120, flag);
  convert_k<<<1024, 256, 0, stream>>>(d_in[5], wqb_bf, (long)3072 * 1536, flag);
  convert_k<<<1024, 256, 0, stream>>>(d_in[6], wkva_bf, (long)576 * 5120, flag);
  convert_k<<<1024, 256, 0, stream>>>(d_in[8], wkvb_bf, (long)4096 * 512, flag);
  convert_k<<<1024, 256, 0, stream>>>(d_in[9], wo_bf, (long)5120 * 2048, flag);
  convert_k<<<64, 256, 0, stream>>>(d_in[10], cos_bf, (long)2048 * 64, flag);
  convert_k<<<64, 256, 0, stream>>>(d_in[11], sin_bf, (long)2048 * 64, flag);
  convert_k<<<2, 256, 0, stream>>>(d_in[4], qln_bf, 1536, flag);
  convert_k<<<1, 256, 0, stream>>>(d_in[7], kvln_bf, 512, flag);

  // fused q_a + kv_a projection: [4096][2112] = hid @ [wq_a;wkv_a]^T
  gemm_bt<64, 0><<<dim3(33, 32), 256, 0, stream>>>(hid_bf, wqa_bf, qkv, flag, 4096, 2112, 5120, 5120, 5120, 2112);
  rms_k<1536><<<4096, 256, 0, stream>>>(qkv, 2112, qln_bf, qan, 1536);
  gemm_bt<128, 1><<<dim3(24, 32), 256, 0, stream>>>(qan, wqb_bf, qb, flag, 4096, 3072, 1536, 1536, 1536, 3072);
  rms_k<512><<<4096, 256, 0, stream>>>(qkv + 1536, 2112, kvln_bf, ckvn, 512);
  gemm_bt<128, 1><<<dim3(32, 32), 256, 0, stream>>>(ckvn, wkvb_bf, kvb, flag, 4096, 4096, 512, 512, 512, 4096);
  prep_k<<<4096, 192, 0, stream>>>(qb, qkv + 1536, kvb, cos_bf, sin_bf, Qg, Kg);
  attn_k<<<dim3(32, 32), 256, 0, stream>>>(Qg, Kg, kvb, ao);
  gemm_bt<128, 2><<<dim3(40, 32), 256, 0, stream>>>(ao, wo_bf, d_out, flag, 4096, 5120, 2048, 2048, 2048, 5120);
}

// Round 6
// 805.757 us; speedup vs baseline: 1.0349x; 1.0349x over previous
//
#include <hip/hip_runtime.h>
#include <hip/hip_bf16.h>

// DeepSeek MLA attention forward, MI355X.
// Round 8: 2-phase double-buffered GEMM (T3 minimum recipe).
//  - BK back to 32 (BK=64 was neutral: barrier COUNT wasn't the cost)
//  - STAGE(next) issued BEFORE ds_read+MFMA of current tile; the single
//    end-of-iter barrier drains loads issued ~200+ cyc earlier -> HBM/L2
//    latency hides under compute instead of sitting serial in every k-step
//  - LDS 32 KB (BN=128) / 24 KB (BN=64) -> 5-6 blocks/CU
// attn (round-5, proven), fused qkv_a layout (round-6), converts/rms/prep
// unchanged.

typedef __attribute__((ext_vector_type(8))) __bf16 bf16x8;
typedef __attribute__((ext_vector_type(4))) __bf16 bf16x4;
typedef __attribute__((ext_vector_type(4))) float f32x4;

#define MFMA_BF16(a, b, c) __builtin_amdgcn_mfma_f32_16x16x32_bf16((a), (b), (c), 0, 0, 0)

__device__ __forceinline__ void async_load16(const void* g, void* l) {
  __builtin_amdgcn_global_load_lds(
      (const __attribute__((address_space(1))) void*)g,
      (__attribute__((address_space(3))) void*)l, 16, 0, 0);
}

// ---------------------------------------------------------------------------
// Dtype sniffer: votes 1 (bf16) / 0 (fp32) into flag[0].
// ---------------------------------------------------------------------------
__global__ void sniff_k(const unsigned int* __restrict__ u, int* __restrict__ flag) {
  int t = threadIdx.x;
  unsigned v = u[t];
  int e = (v >> 7) & 0xFF;
  int s = (e >= 96 && e <= 160) ? 1 : 0;
#pragma unroll
  for (int off = 32; off >= 1; off >>= 1) s += __shfl_xor(s, off);
  __shared__ int cnt[4];
  if ((t & 63) == 0) cnt[t >> 6] = s;
  __syncthreads();
  if (t == 0) flag[0] = (cnt[0] + cnt[1] + cnt[2] + cnt[3] >= 128) ? 1 : 0;
}

// Convert input (fp32 or bf16 per flag) to bf16. n must be a multiple of 4.
__global__ void convert_k(const void* __restrict__ in, __bf16* __restrict__ out,
                          long n, const int* __restrict__ flagp) {
  const int mode = *flagp;
  const long stride = (long)gridDim.x * blockDim.x;
  for (long t = blockIdx.x * (long)blockDim.x + threadIdx.x; t * 4 < n; t += stride) {
    long i = t * 4;
    if (mode) {
      *(uint2*)(out + i) = ((const uint2*)in)[t];
    } else {
      float4 v = ((const float4*)in)[t];
      out[i + 0] = (__bf16)v.x;
      out[i + 1] = (__bf16)v.y;
      out[i + 2] = (__bf16)v.z;
      out[i + 3] = (__bf16)v.w;
    }
  }
}

// ---------------------------------------------------------------------------
// GEMM: C[M,N] = A[M,K] @ B[N,K]^T. 2-phase double-buffered staging:
// prologue stages buf0; each iter stages buf^1 for k+BK, then computes buf.
// The end-of-iter __syncthreads (vmcnt0+lgkmcnt0+barrier) both publishes the
// prefetched tile and guarantees buf^1's readers from iter t-1 are done.
// OUTMODE: 0 = fp32 out, 1 = bf16 out, 2 = runtime flag (1->bf16, 0->fp32).
// ---------------------------------------------------------------------------
template <int BN, int OUTMODE>
__global__ __launch_bounds__(256) void gemm_bt(
    const __bf16* __restrict__ A, const __bf16* __restrict__ B,
    void* __restrict__ Cv, const int* __restrict__ flagp,
    int M, int N, int K, int lda, int ldb, int ldc) {
  constexpr int BM = 128, BK = 32;
  constexpr int NT = (BN == 128) ? 4 : 2;
  constexpr int BCH = (BN * BK) / 512;  // B chunks per tile
  __shared__ __align__(16) __bf16 As[2][BM * BK];
  __shared__ __align__(16) __bf16 Bs[2][BN * BK];
  const int tid = threadIdx.x;
  const int wave = tid >> 6, lane = tid & 63;
  const int m16 = lane & 15, quad = lane >> 4;
  const int m0 = blockIdx.y * BM, n0 = blockIdx.x * BN;
  const int wm = (wave >> 1) * 64;
  const int wn = (wave & 1) * (BN / 2);
  const int ar = lane >> 2;
  const int ak = (lane & 3) * 8;

  f32x4 acc[4][NT];
#pragma unroll
  for (int mt = 0; mt < 4; ++mt)
#pragma unroll
    for (int nt = 0; nt < NT; ++nt) acc[mt][nt] = (f32x4){0.f, 0.f, 0.f, 0.f};

  // stage one BKx(BM|BN) tile into buffer `buf`
  auto stage = [&](int buf, int k0) {
#pragma unroll
    for (int c = 0; c < 2; ++c) {
      int q = wave * 2 + c;
      const __bf16* g = A + (size_t)(m0 + q * 16 + ar) * lda + k0 + ak;
      async_load16(g, (void*)(As[buf] + q * 512));
    }
#pragma unroll
    for (int c = 0; c < BCH / 4; ++c) {
      int q = wave * (BCH / 4) + c;
      const __bf16* g = B + (size_t)(n0 + q * 16 + ar) * ldb + k0 + ak;
      async_load16(g, (void*)(Bs[buf] + q * 512));
    }
  };

  stage(0, 0);
  __syncthreads();  // publish tile 0
  int cur = 0;
  for (int k0 = 0; k0 < K; k0 += BK) {
    if (k0 + BK < K) stage(cur ^ 1, k0 + BK);  // prefetch next tile
    bf16x8 af[4], bfv[NT];
#pragma unroll
    for (int mt = 0; mt < 4; ++mt)
      af[mt] = *(const bf16x8*)&As[cur][(wm + mt * 16 + m16) * BK + quad * 8];
#pragma unroll
    for (int nt = 0; nt < NT; ++nt)
      bfv[nt] = *(const bf16x8*)&Bs[cur][(wn + nt * 16 + m16) * BK + quad * 8];
#pragma unroll
    for (int mt = 0; mt < 4; ++mt)
#pragma unroll
      for (int nt = 0; nt < NT; ++nt)
        acc[mt][nt] = MFMA_BF16(af[mt], bfv[nt], acc[mt][nt]);
    __syncthreads();  // drain prefetch (issued before compute) + publish
    cur ^= 1;
  }
  bool obf16;
  if constexpr (OUTMODE == 2) obf16 = (*flagp != 0);
  else obf16 = (OUTMODE == 1);
#pragma unroll
  for (int mt = 0; mt < 4; ++mt)
#pragma unroll
    for (int nt = 0; nt < NT; ++nt)
#pragma unroll
      for (int rg = 0; rg < 4; ++rg) {
        size_t row = m0 + wm + mt * 16 + quad * 4 + rg;
        size_t col = n0 + wn + nt * 16 + m16;
        float v = acc[mt][nt][rg];
        if (obf16)
          ((__bf16*)Cv)[row * (size_t)ldc + col] = (__bf16)v;
        else
          ((float*)Cv)[row * (size_t)ldc + col] = v;
      }
}

// ---------------------------------------------------------------------------
// RMSNorm: fp32 in -> bf16 out, one block (256 thr) per row.
// ---------------------------------------------------------------------------
template <int COLS>
__global__ __launch_bounds__(256) void rms_k(const float* __restrict__ in, int ldin,
                                             const __bf16* __restrict__ w,
                                             __bf16* __restrict__ out, int ldout) {
  constexpr int PER = COLS / 256;
  const int row = blockIdx.x, tid = threadIdx.x;
  const float* x = in + (size_t)row * ldin;
  float v[PER];
  float ss = 0.f;
#pragma unroll
  for (int i = 0; i < PER; ++i) {
    v[i] = x[tid + i * 256];
    ss += v[i] * v[i];
  }
#pragma unroll
  for (int off = 32; off >= 1; off >>= 1) ss += __shfl_xor(ss, off);
  __shared__ float red[4];
  if ((tid & 63) == 0) red[tid >> 6] = ss;
  __syncthreads();
  ss = red[0] + red[1] + red[2] + red[3];
  float sc = rsqrtf(ss / (float)COLS + 1e-6f);
#pragma unroll
  for (int i = 0; i < PER; ++i)
    out[(size_t)row * ldout + tid + i * 256] =
        (__bf16)(v[i] * sc * (float)w[tid + i * 256]);
}

// ---------------------------------------------------------------------------
// Prep: build Q[bh][s][192], K[bh][s][192] with RoPE on last 64 dims.
// Q is pre-scaled by (1/sqrt(192))*log2(e) so attn softmax runs in exp2
// domain with no per-score multiply.
// ckv points at column 1536 of the fused [4096][2112] fp32 projection buffer
// (row stride 2112); k_pe RoPE input is its columns 512..575 (pre-norm).
// ---------------------------------------------------------------------------
#define QK_SCALE (0.07216878364870323f * 1.4426950408889634f)

__global__ void prep_k(const __bf16* __restrict__ qb,    // [4096][3072]
                       const float* __restrict__ ckv,    // [4096][*] fp32, ld=2112
                       const __bf16* __restrict__ kvb,   // [4096][4096]
                       const __bf16* __restrict__ cosp,  // [2048][64] bf16
                       const __bf16* __restrict__ sinp,
                       __bf16* __restrict__ Qg, __bf16* __restrict__ Kg) {
  const int bs = blockIdx.x;  // b*2048 + s
  const int s = bs & 2047, b = bs >> 11;
  const int d = threadIdx.x;  // 0..191
  float c = 0.f, sn = 0.f, kpe = 0.f;
  if (d >= 128) {
    int i = d - 128;
    c = (float)cosp[s * 64 + i];
    sn = (float)sinp[s * 64 + i];
    const float* ck = ckv + (size_t)bs * 2112 + 512;
    if (i < 32)
      kpe = ck[2 * i] * c - ck[2 * i + 1] * sn;
    else {
      int j = i - 32;
      kpe = ck[2 * j + 1] * c + ck[2 * j] * sn;
    }
  }
  for (int h = 0; h < 16; ++h) {
    size_t orow = ((size_t)(b * 16 + h) * 2048 + s) * 192 + d;
    const __bf16* qr = qb + (size_t)bs * 3072 + h * 192;
    float qv;
    if (d < 128)
      qv = (float)qr[d];
    else {
      int i = d - 128;
      if (i < 32)
        qv = (float)qr[128 + 2 * i] * c - (float)qr[128 + 2 * i + 1] * sn;
      else {
        int j = i - 32;
        qv = (float)qr[128 + 2 * j + 1] * c + (float)qr[128 + 2 * j] * sn;
      }
    }
    Qg[orow] = (__bf16)(qv * QK_SCALE);
    float kval = (d < 128) ? (float)kvb[(size_t)bs * 4096 + h * 256 + d] : kpe;
    Kg[orow] = (__bf16)kval;
  }
}

// ---------------------------------------------------------------------------
// Causal flash attention, round-5 structure (unchanged).
// 64 q-rows per block (16 per wave), 1024 blocks. LDS 52 KB -> 3 blocks/CU.
// XCD-affine bh map, longest-first q-tiles, reg-prefetched K/V staging,
// exp2-domain softmax, diagonal-only mask, defer-rescale (THR=8).
// launch_bounds(256,2): (256,3) forced 84 VGPR -> spills -> 1.2 GB scratch.
// ---------------------------------------------------------------------------
__global__ __launch_bounds__(256, 2) void attn_k(const __bf16* __restrict__ Qg,
                                                 const __bf16* __restrict__ Kg,
                                                 const __bf16* __restrict__ kvb,
                                                 __bf16* __restrict__ Og) {
  constexpr int S = 2048;
  __shared__ __align__(16) __bf16 Ks[64 * 200];   // 25.6 KB
  __shared__ __align__(16) __bf16 Vt[128 * 72];   // 18.4 KB
  __shared__ __align__(16) __bf16 Ps[64 * 72];    //  9.2 KB
  // work mapping: L in [0,1024). xcd class = L&7; heavy xt first.
  const int L = blockIdx.x + (blockIdx.y << 5);
  const int xcd = L & 7, m = L >> 3;
  const int xt = 31 - (m >> 2);          // q-tile 31..0, longest first
  const int bh = ((m & 3) << 3) | xcd;   // bh&7 == L&7
  const int b = bh >> 4, h = bh & 15;
  const int i0 = xt * 64;
  const int tid = threadIdx.x, wave = tid >> 6, lane = tid & 63;
  const int m16 = lane & 15, quad = lane >> 4;
  // V-transpose thread mapping: 4 s-rows x 8 d-cols per thread
  const int sb = (tid & 15) * 4, d0 = (tid >> 4) * 8;

  // Q fragments resident in registers (16 q-rows per wave)
  bf16x8 qf[6];
  const __bf16* Qb = Qg + ((size_t)bh * S + i0 + wave * 16) * 192;
#pragma unroll
  for (int kc = 0; kc < 6; ++kc)
    qf[kc] = *(const bf16x8*)(Qb + m16 * 192 + kc * 32 + quad * 8);

  f32x4 oacc[8];
#pragma unroll
  for (int nt = 0; nt < 8; ++nt) oacc[nt] = (f32x4){0.f, 0.f, 0.f, 0.f};
  float mrow[4], lrow[4];
#pragma unroll
  for (int rg = 0; rg < 4; ++rg) {
    mrow[rg] = -1e30f;
    lrow[rg] = 0.f;
  }

  const __bf16* Kbase = Kg + (size_t)bh * S * 192;
  const __bf16* Vbase = kvb + (size_t)b * S * 4096 + h * 256 + 128 + d0;
  const int ntl = xt + 1;

  // K staging geometry: 1536 chunks of 8 = 64 rows x 24 chunks
  int krow[6], kcol[6];
#pragma unroll
  for (int c = 0; c < 6; ++c) {
    int chunk = tid + c * 256;
    krow[c] = chunk / 24;
    kcol[c] = (chunk % 24) * 8;
  }

  // prefetch tile 0
  bf16x8 kr[6], vr[4];
#pragma unroll
  for (int c = 0; c < 6; ++c)
    kr[c] = *(const bf16x8*)(Kbase + (size_t)krow[c] * 192 + kcol[c]);
#pragma unroll
  for (int r = 0; r < 4; ++r)
    vr[r] = *(const bf16x8*)(Vbase + (size_t)(sb + r) * 4096);

  for (int t = 0; t < ntl; ++t) {
    const int kt0 = t * 64;
    __syncthreads();  // B1: prev compute done; also drains prefetched loads
    // regs -> LDS
#pragma unroll
    for (int c = 0; c < 6; ++c)
      *(bf16x8*)&Ks[krow[c] * 200 + kcol[c]] = kr[c];
#pragma unroll
    for (int j = 0; j < 8; ++j) {
      bf16x4 wv = {vr[0][j], vr[1][j], vr[2][j], vr[3][j]};
      *(bf16x4*)&Vt[(d0 + j) * 72 + sb] = wv;
    }
    __syncthreads();  // B2: LDS visible (no vmem in flight here)
    // prefetch tile t+1 — stays in flight across the whole compute phase
    if (t + 1 < ntl) {
      const __bf16* Kb = Kbase + (size_t)(kt0 + 64) * 192;
#pragma unroll
      for (int c = 0; c < 6; ++c)
        kr[c] = *(const bf16x8*)(Kb + (size_t)krow[c] * 192 + kcol[c]);
      const __bf16* Vb = Vbase + (size_t)(kt0 + 64) * 4096;
#pragma unroll
      for (int r = 0; r < 4; ++r)
        vr[r] = *(const bf16x8*)(Vb + (size_t)(sb + r) * 4096);
    }

    // S = Q K^T  (already scaled: Qg carries scale*log2e)
    f32x4 sacc[4];
#pragma unroll
    for (int nt = 0; nt < 4; ++nt) sacc[nt] = (f32x4){0.f, 0.f, 0.f, 0.f};
#pragma unroll
    for (int kc = 0; kc < 6; ++kc) {
      bf16x8 bv[4];
#pragma unroll
      for (int nt = 0; nt < 4; ++nt)
        bv[nt] = *(const bf16x8*)&Ks[(nt * 16 + m16) * 200 + kc * 32 + quad * 8];
#pragma unroll
      for (int nt = 0; nt < 4; ++nt)
        sacc[nt] = MFMA_BF16(qf[kc], bv[nt], sacc[nt]);
    }
    // causal mask — only the diagonal tile can mask (kt0 == i0 there)
    if (t == ntl - 1) {
#pragma unroll
      for (int nt = 0; nt < 4; ++nt)
#pragma unroll
        for (int rg = 0; rg < 4; ++rg) {
          int qrow = wave * 16 + quad * 4 + rg;  // local row
          int kcl = nt * 16 + m16;               // local col
          if (kcl > qrow) sacc[nt][rg] = -1e30f;
        }
    }
    // online softmax (exp2 domain)
    float tm[4];
#pragma unroll
    for (int rg = 0; rg < 4; ++rg) {
      float v = fmaxf(fmaxf(sacc[0][rg], sacc[1][rg]),
                      fmaxf(sacc[2][rg], sacc[3][rg]));
      v = fmaxf(v, __shfl_xor(v, 1));
      v = fmaxf(v, __shfl_xor(v, 2));
      v = fmaxf(v, __shfl_xor(v, 4));
      v = fmaxf(v, __shfl_xor(v, 8));
      tm[rg] = v;
    }
    bool nomax = true;
#pragma unroll
    for (int rg = 0; rg < 4; ++rg) nomax = nomax && (tm[rg] <= mrow[rg] + 8.f);
    if (__all(nomax)) {
      // deferred path: keep stale max (p bounded by 2^8), no O-rescale
#pragma unroll
      for (int rg = 0; rg < 4; ++rg) {
        float rs = 0.f;
#pragma unroll
        for (int nt = 0; nt < 4; ++nt) {
          float p = exp2f(sacc[nt][rg] - mrow[rg]);
          sacc[nt][rg] = p;
          rs += p;
        }
        rs += __shfl_xor(rs, 1);
        rs += __shfl_xor(rs, 2);
        rs += __shfl_xor(rs, 4);
        rs += __shfl_xor(rs, 8);
        lrow[rg] += rs;
      }
    } else {
#pragma unroll
      for (int rg = 0; rg < 4; ++rg) {
        float nm = fmaxf(mrow[rg], tm[rg]);
        float alpha = exp2f(mrow[rg] - nm);
        mrow[rg] = nm;
        float rs = 0.f;
#pragma unroll
        for (int nt = 0; nt < 4; ++nt) {
          float p = exp2f(sacc[nt][rg] - nm);
          sacc[nt][rg] = p;
          rs += p;
        }
        rs += __shfl_xor(rs, 1);
        rs += __shfl_xor(rs, 2);
        rs += __shfl_xor(rs, 4);
        rs += __shfl_xor(rs, 8);
        lrow[rg] = lrow[rg] * alpha + rs;
#pragma unroll
        for (int nt = 0; nt < 8; ++nt) oacc[nt][rg] *= alpha;
      }
    }
    // P -> LDS (wave-private rows, no barrier needed)
#pragma unroll
    for (int nt = 0; nt < 4; ++nt)
#pragma unroll
      for (int rg = 0; rg < 4; ++rg)
        Ps[(wave * 16 + quad * 4 + rg) * 72 + nt * 16 + m16] =
            (__bf16)sacc[nt][rg];
    // O += P V
#pragma unroll
    for (int kc2 = 0; kc2 < 2; ++kc2) {
      bf16x8 af = *(const bf16x8*)&Ps[(wave * 16 + m16) * 72 + kc2 * 32 + quad * 8];
#pragma unroll
      for (int nt = 0; nt < 8; ++nt) {
        bf16x8 bv = *(const bf16x8*)&Vt[(nt * 16 + m16) * 72 + kc2 * 32 + quad * 8];
        oacc[nt] = MFMA_BF16(af, bv, oacc[nt]);
      }
    }
  }
  // epilogue
#pragma unroll
  for (int nt = 0; nt < 8; ++nt)
#pragma unroll
    for (int rg = 0; rg < 4; ++rg) {
      int sg = i0 + wave * 16 + quad * 4 + rg;
      int d = nt * 16 + m16;
      float val = oacc[nt][rg] / lrow[rg];
      Og[((size_t)b * S + sg) * 2048 + h * 128 + d] = (__bf16)val;
    }
}

// ---------------------------------------------------------------------------
extern "C" void kernel_launch(void* const* d_in, const int* in_sizes, int n_in,
                              void* d_out, int out_size, void* d_ws, size_t ws_size,
                              hipStream_t stream) {
  char* w0 = (char*)d_ws;
  int* flag = (int*)w0;
  char* w = w0 + 256;
  __bf16* hid_bf = (__bf16*)w;   w += (size_t)4096 * 5120 * 2;
  // wqa_bf and wkva_bf adjacent -> contiguous fused weight [2112][5120]
  __bf16* wqa_bf = (__bf16*)w;   w += (size_t)1536 * 5120 * 2;
  __bf16* wkva_bf = (__bf16*)w;  w += (size_t)576 * 5120 * 2;
  __bf16* wqb_bf = (__bf16*)w;   w += (size_t)3072 * 1536 * 2;
  __bf16* wkvb_bf = (__bf16*)w;  w += (size_t)4096 * 512 * 2;
  __bf16* wo_bf = (__bf16*)w;    w += (size_t)5120 * 2048 * 2;
  __bf16* cos_bf = (__bf16*)w;   w += (size_t)2048 * 64 * 2;
  __bf16* sin_bf = (__bf16*)w;   w += (size_t)2048 * 64 * 2;
  __bf16* qln_bf = (__bf16*)w;   w += 4096;
  __bf16* kvln_bf = (__bf16*)w;  w += 4096;
  float* qkv = (float*)w;        w += (size_t)4096 * 2112 * 4;  // [q_a(1536)|ckv(576)]
  __bf16* qan = (__bf16*)w;      w += (size_t)4096 * 1536 * 2;
  __bf16* qb = (__bf16*)w;       w += (size_t)4096 * 3072 * 2;
  __bf16* ckvn = (__bf16*)w;     w += (size_t)4096 * 512 * 2;
  __bf16* kvb = (__bf16*)w;      w += (size_t)4096 * 4096 * 2;
  // Overlays: Qg over hid_bf (dead after fused qkv_a gemm); Kg over
  // wqa_bf+wkva_bf+wqb_bf (all dead before prep_k); ao over qkv (dead after
  // rms + prep_k, attn writes it afterwards).
  __bf16* Qg = hid_bf;
  __bf16* Kg = wqa_bf;
  __bf16* ao = (__bf16*)qkv;

  sniff_k<<<1, 256, 0, stream>>>((const unsigned int*)d_in[0], flag);
  convert_k<<<1024, 256, 0, stream>>>(d_in[0], hid_bf, (long)4096 * 5120, flag);
  convert_k<<<1024, 256, 0, stream>>>(d_in[3], wqa_bf, (long)1536 * 5120, flag);
  convert_k<<<1024, 256, 0, stream>>>(d_in[5], wqb_bf, (long)3072 * 1536, flag);
  convert_k<<<1024, 256, 0, stream>>>(d_in[6], wkva_bf, (long)576 * 5120, flag);
  convert_k<<<1024, 256, 0, stream>>>(d_in[8], wkvb_bf, (long)4096 * 512, flag);
  convert_k<<<1024, 256, 0, stream>>>(d_in[9], wo_bf, (long)5120 * 2048, flag);
  convert_k<<<64, 256, 0, stream>>>(d_in[10], cos_bf, (long)2048 * 64, flag);
  convert_k<<<64, 256, 0, stream>>>(d_in[11], sin_bf, (long)2048 * 64, flag);
  convert_k<<<2, 256, 0, stream>>>(d_in[4], qln_bf, 1536, flag);
  convert_k<<<1, 256, 0, stream>>>(d_in[7], kvln_bf, 512, flag);

  // fused q_a + kv_a projection: [4096][2112] = hid @ [wq_a;wkv_a]^T
  gemm_bt<64, 0><<<dim3(33, 32), 256, 0, stream>>>(hid_bf, wqa_bf, qkv, flag, 4096, 2112, 5120, 5120, 5120, 2112);
  rms_k<1536><<<4096, 256, 0, stream>>>(qkv, 2112, qln_bf, qan, 1536);
  gemm_bt<128, 1><<<dim3(24, 32), 256, 0, stream>>>(qan, wqb_bf, qb, flag, 4096, 3072, 1536, 1536, 1536, 3072);
  rms_k<512><<<4096, 256, 0, stream>>>(qkv + 1536, 2112, kvln_bf, ckvn, 512);
  gemm_bt<128, 1><<<dim3(32, 32), 256, 0, stream>>>(ckvn, wkvb_bf, kvb, flag, 4096, 4096, 512, 512, 512, 4096);
  prep_k<<<4096, 192, 0, stream>>>(qb, qkv + 1536, kvb, cos_bf, sin_bf, Qg, Kg);
  attn_k<<<dim3(32, 32), 256, 0, stream>>>(Qg, Kg, kvb, ao);
  gemm_bt<128, 2><<<dim3(40, 32), 256, 0, stream>>>(ao, wo_bf, d_out, flag, 4096, 5120, 2048, 2048, 2048, 5120);
}

// Round 7
// 766.876 us; speedup vs baseline: 1.0874x; 1.0507x over previous
//
#include <hip/hip_runtime.h>
#include <hip/hip_bf16.h>

// DeepSeek MLA attention forward, MI355X.
// Round 9: XCD row-band remap in gemm_bt (T1 chunked variant).
//  - blocks sharing an A-panel (same grid row) were round-robined across all
//    8 XCDs -> every XCD fetched every A panel (FETCH 292 MB vs 62 ideal),
//    ~900-cyc HBM misses each k-step that the 1-deep pipeline can't hide.
//  - remap: XCD c owns grid-row band y in [c*ny/8,(c+1)*ny/8) -> A k-slices
//    fetched once per XCD, staging becomes ~200-cyc L2 hits; B re-reads
//    absorbed by 256 MB L3. Bijective (ny=32 for all 4 GEMMs; guarded).
// 2-phase dbuf staging (round-8), attn (round-5), fused qkv_a (round-6),
// converts/rms/prep unchanged.

typedef __attribute__((ext_vector_type(8))) __bf16 bf16x8;
typedef __attribute__((ext_vector_type(4))) __bf16 bf16x4;
typedef __attribute__((ext_vector_type(4))) float f32x4;

#define MFMA_BF16(a, b, c) __builtin_amdgcn_mfma_f32_16x16x32_bf16((a), (b), (c), 0, 0, 0)

__device__ __forceinline__ void async_load16(const void* g, void* l) {
  __builtin_amdgcn_global_load_lds(
      (const __attribute__((address_space(1))) void*)g,
      (__attribute__((address_space(3))) void*)l, 16, 0, 0);
}

// ---------------------------------------------------------------------------
// Dtype sniffer: votes 1 (bf16) / 0 (fp32) into flag[0].
// ---------------------------------------------------------------------------
__global__ void sniff_k(const unsigned int* __restrict__ u, int* __restrict__ flag) {
  int t = threadIdx.x;
  unsigned v = u[t];
  int e = (v >> 7) & 0xFF;
  int s = (e >= 96 && e <= 160) ? 1 : 0;
#pragma unroll
  for (int off = 32; off >= 1; off >>= 1) s += __shfl_xor(s, off);
  __shared__ int cnt[4];
  if ((t & 63) == 0) cnt[t >> 6] = s;
  __syncthreads();
  if (t == 0) flag[0] = (cnt[0] + cnt[1] + cnt[2] + cnt[3] >= 128) ? 1 : 0;
}

// Convert input (fp32 or bf16 per flag) to bf16. n must be a multiple of 4.
__global__ void convert_k(const void* __restrict__ in, __bf16* __restrict__ out,
                          long n, const int* __restrict__ flagp) {
  const int mode = *flagp;
  const long stride = (long)gridDim.x * blockDim.x;
  for (long t = blockIdx.x * (long)blockDim.x + threadIdx.x; t * 4 < n; t += stride) {
    long i = t * 4;
    if (mode) {
      *(uint2*)(out + i) = ((const uint2*)in)[t];
    } else {
      float4 v = ((const float4*)in)[t];
      out[i + 0] = (__bf16)v.x;
      out[i + 1] = (__bf16)v.y;
      out[i + 2] = (__bf16)v.z;
      out[i + 3] = (__bf16)v.w;
    }
  }
}

// ---------------------------------------------------------------------------
// GEMM: C[M,N] = A[M,K] @ B[N,K]^T. 2-phase double-buffered staging +
// XCD row-band remap (XCD c owns a contiguous band of grid rows so that
// all blocks sharing an A panel land on one XCD's L2).
// OUTMODE: 0 = fp32 out, 1 = bf16 out, 2 = runtime flag (1->bf16, 0->fp32).
// ---------------------------------------------------------------------------
template <int BN, int OUTMODE>
__global__ __launch_bounds__(256) void gemm_bt(
    const __bf16* __restrict__ A, const __bf16* __restrict__ B,
    void* __restrict__ Cv, const int* __restrict__ flagp,
    int M, int N, int K, int lda, int ldb, int ldc) {
  constexpr int BM = 128, BK = 32;
  constexpr int NT = (BN == 128) ? 4 : 2;
  constexpr int BCH = (BN * BK) / 512;  // B chunks per tile
  __shared__ __align__(16) __bf16 As[2][BM * BK];
  __shared__ __align__(16) __bf16 Bs[2][BN * BK];
  const int tid = threadIdx.x;
  const int wave = tid >> 6, lane = tid & 63;
  const int m16 = lane & 15, quad = lane >> 4;

  // XCD row-band remap (bijective when gridDim.y % 8 == 0; else identity).
  int bx = blockIdx.x, by = blockIdx.y;
  if ((gridDim.y & 7) == 0) {
    const int Lid = blockIdx.x + gridDim.x * blockIdx.y;
    const int band = gridDim.y >> 3;
    const int xcd = Lid & 7, i = Lid >> 3;
    by = xcd * band + (i % band);
    bx = i / band;
  }
  const int m0 = by * BM, n0 = bx * BN;

  const int wm = (wave >> 1) * 64;
  const int wn = (wave & 1) * (BN / 2);
  const int ar = lane >> 2;
  const int ak = (lane & 3) * 8;

  f32x4 acc[4][NT];
#pragma unroll
  for (int mt = 0; mt < 4; ++mt)
#pragma unroll
    for (int nt = 0; nt < NT; ++nt) acc[mt][nt] = (f32x4){0.f, 0.f, 0.f, 0.f};

  // stage one BKx(BM|BN) tile into buffer `buf`
  auto stage = [&](int buf, int k0) {
#pragma unroll
    for (int c = 0; c < 2; ++c) {
      int q = wave * 2 + c;
      const __bf16* g = A + (size_t)(m0 + q * 16 + ar) * lda + k0 + ak;
      async_load16(g, (void*)(As[buf] + q * 512));
    }
#pragma unroll
    for (int c = 0; c < BCH / 4; ++c) {
      int q = wave * (BCH / 4) + c;
      const __bf16* g = B + (size_t)(n0 + q * 16 + ar) * ldb + k0 + ak;
      async_load16(g, (void*)(Bs[buf] + q * 512));
    }
  };

  stage(0, 0);
  __syncthreads();  // publish tile 0
  int cur = 0;
  for (int k0 = 0; k0 < K; k0 += BK) {
    if (k0 + BK < K) stage(cur ^ 1, k0 + BK);  // prefetch next tile
    bf16x8 af[4], bfv[NT];
#pragma unroll
    for (int mt = 0; mt < 4; ++mt)
      af[mt] = *(const bf16x8*)&As[cur][(wm + mt * 16 + m16) * BK + quad * 8];
#pragma unroll
    for (int nt = 0; nt < NT; ++nt)
      bfv[nt] = *(const bf16x8*)&Bs[cur][(wn + nt * 16 + m16) * BK + quad * 8];
#pragma unroll
    for (int mt = 0; mt < 4; ++mt)
#pragma unroll
      for (int nt = 0; nt < NT; ++nt)
        acc[mt][nt] = MFMA_BF16(af[mt], bfv[nt], acc[mt][nt]);
    __syncthreads();  // drain prefetch (issued before compute) + publish
    cur ^= 1;
  }
  bool obf16;
  if constexpr (OUTMODE == 2) obf16 = (*flagp != 0);
  else obf16 = (OUTMODE == 1);
#pragma unroll
  for (int mt = 0; mt < 4; ++mt)
#pragma unroll
    for (int nt = 0; nt < NT; ++nt)
#pragma unroll
      for (int rg = 0; rg < 4; ++rg) {
        size_t row = m0 + wm + mt * 16 + quad * 4 + rg;
        size_t col = n0 + wn + nt * 16 + m16;
        float v = acc[mt][nt][rg];
        if (obf16)
          ((__bf16*)Cv)[row * (size_t)ldc + col] = (__bf16)v;
        else
          ((float*)Cv)[row * (size_t)ldc + col] = v;
      }
}

// ---------------------------------------------------------------------------
// RMSNorm: fp32 in -> bf16 out, one block (256 thr) per row.
// ---------------------------------------------------------------------------
template <int COLS>
__global__ __launch_bounds__(256) void rms_k(const float* __restrict__ in, int ldin,
                                             const __bf16* __restrict__ w,
                                             __bf16* __restrict__ out, int ldout) {
  constexpr int PER = COLS / 256;
  const int row = blockIdx.x, tid = threadIdx.x;
  const float* x = in + (size_t)row * ldin;
  float v[PER];
  float ss = 0.f;
#pragma unroll
  for (int i = 0; i < PER; ++i) {
    v[i] = x[tid + i * 256];
    ss += v[i] * v[i];
  }
#pragma unroll
  for (int off = 32; off >= 1; off >>= 1) ss += __shfl_xor(ss, off);
  __shared__ float red[4];
  if ((tid & 63) == 0) red[tid >> 6] = ss;
  __syncthreads();
  ss = red[0] + red[1] + red[2] + red[3];
  float sc = rsqrtf(ss / (float)COLS + 1e-6f);
#pragma unroll
  for (int i = 0; i < PER; ++i)
    out[(size_t)row * ldout + tid + i * 256] =
        (__bf16)(v[i] * sc * (float)w[tid + i * 256]);
}

// ---------------------------------------------------------------------------
// Prep: build Q[bh][s][192], K[bh][s][192] with RoPE on last 64 dims.
// Q is pre-scaled by (1/sqrt(192))*log2(e) so attn softmax runs in exp2
// domain with no per-score multiply.
// ckv points at column 1536 of the fused [4096][2112] fp32 projection buffer
// (row stride 2112); k_pe RoPE input is its columns 512..575 (pre-norm).
// ---------------------------------------------------------------------------
#define QK_SCALE (0.07216878364870323f * 1.4426950408889634f)

__global__ void prep_k(const __bf16* __restrict__ qb,    // [4096][3072]
                       const float* __restrict__ ckv,    // [4096][*] fp32, ld=2112
                       const __bf16* __restrict__ kvb,   // [4096][4096]
                       const __bf16* __restrict__ cosp,  // [2048][64] bf16
                       const __bf16* __restrict__ sinp,
                       __bf16* __restrict__ Qg, __bf16* __restrict__ Kg) {
  const int bs = blockIdx.x;  // b*2048 + s
  const int s = bs & 2047, b = bs >> 11;
  const int d = threadIdx.x;  // 0..191
  float c = 0.f, sn = 0.f, kpe = 0.f;
  if (d >= 128) {
    int i = d - 128;
    c = (float)cosp[s * 64 + i];
    sn = (float)sinp[s * 64 + i];
    const float* ck = ckv + (size_t)bs * 2112 + 512;
    if (i < 32)
      kpe = ck[2 * i] * c - ck[2 * i + 1] * sn;
    else {
      int j = i - 32;
      kpe = ck[2 * j + 1] * c + ck[2 * j] * sn;
    }
  }
  for (int h = 0; h < 16; ++h) {
    size_t orow = ((size_t)(b * 16 + h) * 2048 + s) * 192 + d;
    const __bf16* qr = qb + (size_t)bs * 3072 + h * 192;
    float qv;
    if (d < 128)
      qv = (float)qr[d];
    else {
      int i = d - 128;
      if (i < 32)
        qv = (float)qr[128 + 2 * i] * c - (float)qr[128 + 2 * i + 1] * sn;
      else {
        int j = i - 32;
        qv = (float)qr[128 + 2 * j + 1] * c + (float)qr[128 + 2 * j] * sn;
      }
    }
    Qg[orow] = (__bf16)(qv * QK_SCALE);
    float kval = (d < 128) ? (float)kvb[(size_t)bs * 4096 + h * 256 + d] : kpe;
    Kg[orow] = (__bf16)kval;
  }
}

// ---------------------------------------------------------------------------
// Causal flash attention, round-5 structure (unchanged).
// 64 q-rows per block (16 per wave), 1024 blocks. LDS 52 KB -> 3 blocks/CU.
// XCD-affine bh map, longest-first q-tiles, reg-prefetched K/V staging,
// exp2-domain softmax, diagonal-only mask, defer-rescale (THR=8).
// launch_bounds(256,2): (256,3) forced 84 VGPR -> spills -> 1.2 GB scratch.
// ---------------------------------------------------------------------------
__global__ __launch_bounds__(256, 2) void attn_k(const __bf16* __restrict__ Qg,
                                                 const __bf16* __restrict__ Kg,
                                                 const __bf16* __restrict__ kvb,
                                                 __bf16* __restrict__ Og) {
  constexpr int S = 2048;
  __shared__ __align__(16) __bf16 Ks[64 * 200];   // 25.6 KB
  __shared__ __align__(16) __bf16 Vt[128 * 72];   // 18.4 KB
  __shared__ __align__(16) __bf16 Ps[64 * 72];    //  9.2 KB
  // work mapping: L in [0,1024). xcd class = L&7; heavy xt first.
  const int L = blockIdx.x + (blockIdx.y << 5);
  const int xcd = L & 7, m = L >> 3;
  const int xt = 31 - (m >> 2);          // q-tile 31..0, longest first
  const int bh = ((m & 3) << 3) | xcd;   // bh&7 == L&7
  const int b = bh >> 4, h = bh & 15;
  const int i0 = xt * 64;
  const int tid = threadIdx.x, wave = tid >> 6, lane = tid & 63;
  const int m16 = lane & 15, quad = lane >> 4;
  // V-transpose thread mapping: 4 s-rows x 8 d-cols per thread
  const int sb = (tid & 15) * 4, d0 = (tid >> 4) * 8;

  // Q fragments resident in registers (16 q-rows per wave)
  bf16x8 qf[6];
  const __bf16* Qb = Qg + ((size_t)bh * S + i0 + wave * 16) * 192;
#pragma unroll
  for (int kc = 0; kc < 6; ++kc)
    qf[kc] = *(const bf16x8*)(Qb + m16 * 192 + kc * 32 + quad * 8);

  f32x4 oacc[8];
#pragma unroll
  for (int nt = 0; nt < 8; ++nt) oacc[nt] = (f32x4){0.f, 0.f, 0.f, 0.f};
  float mrow[4], lrow[4];
#pragma unroll
  for (int rg = 0; rg < 4; ++rg) {
    mrow[rg] = -1e30f;
    lrow[rg] = 0.f;
  }

  const __bf16* Kbase = Kg + (size_t)bh * S * 192;
  const __bf16* Vbase = kvb + (size_t)b * S * 4096 + h * 256 + 128 + d0;
  const int ntl = xt + 1;

  // K staging geometry: 1536 chunks of 8 = 64 rows x 24 chunks
  int krow[6], kcol[6];
#pragma unroll
  for (int c = 0; c < 6; ++c) {
    int chunk = tid + c * 256;
    krow[c] = chunk / 24;
    kcol[c] = (chunk % 24) * 8;
  }

  // prefetch tile 0
  bf16x8 kr[6], vr[4];
#pragma unroll
  for (int c = 0; c < 6; ++c)
    kr[c] = *(const bf16x8*)(Kbase + (size_t)krow[c] * 192 + kcol[c]);
#pragma unroll
  for (int r = 0; r < 4; ++r)
    vr[r] = *(const bf16x8*)(Vbase + (size_t)(sb + r) * 4096);

  for (int t = 0; t < ntl; ++t) {
    const int kt0 = t * 64;
    __syncthreads();  // B1: prev compute done; also drains prefetched loads
    // regs -> LDS
#pragma unroll
    for (int c = 0; c < 6; ++c)
      *(bf16x8*)&Ks[krow[c] * 200 + kcol[c]] = kr[c];
#pragma unroll
    for (int j = 0; j < 8; ++j) {
      bf16x4 wv = {vr[0][j], vr[1][j], vr[2][j], vr[3][j]};
      *(bf16x4*)&Vt[(d0 + j) * 72 + sb] = wv;
    }
    __syncthreads();  // B2: LDS visible (no vmem in flight here)
    // prefetch tile t+1 — stays in flight across the whole compute phase
    if (t + 1 < ntl) {
      const __bf16* Kb = Kbase + (size_t)(kt0 + 64) * 192;
#pragma unroll
      for (int c = 0; c < 6; ++c)
        kr[c] = *(const bf16x8*)(Kb + (size_t)krow[c] * 192 + kcol[c]);
      const __bf16* Vb = Vbase + (size_t)(kt0 + 64) * 4096;
#pragma unroll
      for (int r = 0; r < 4; ++r)
        vr[r] = *(const bf16x8*)(Vb + (size_t)(sb + r) * 4096);
    }

    // S = Q K^T  (already scaled: Qg carries scale*log2e)
    f32x4 sacc[4];
#pragma unroll
    for (int nt = 0; nt < 4; ++nt) sacc[nt] = (f32x4){0.f, 0.f, 0.f, 0.f};
#pragma unroll
    for (int kc = 0; kc < 6; ++kc) {
      bf16x8 bv[4];
#pragma unroll
      for (int nt = 0; nt < 4; ++nt)
        bv[nt] = *(const bf16x8*)&Ks[(nt * 16 + m16) * 200 + kc * 32 + quad * 8];
#pragma unroll
      for (int nt = 0; nt < 4; ++nt)
        sacc[nt] = MFMA_BF16(qf[kc], bv[nt], sacc[nt]);
    }
    // causal mask — only the diagonal tile can mask (kt0 == i0 there)
    if (t == ntl - 1) {
#pragma unroll
      for (int nt = 0; nt < 4; ++nt)
#pragma unroll
        for (int rg = 0; rg < 4; ++rg) {
          int qrow = wave * 16 + quad * 4 + rg;  // local row
          int kcl = nt * 16 + m16;               // local col
          if (kcl > qrow) sacc[nt][rg] = -1e30f;
        }
    }
    // online softmax (exp2 domain)
    float tm[4];
#pragma unroll
    for (int rg = 0; rg < 4; ++rg) {
      float v = fmaxf(fmaxf(sacc[0][rg], sacc[1][rg]),
                      fmaxf(sacc[2][rg], sacc[3][rg]));
      v = fmaxf(v, __shfl_xor(v, 1));
      v = fmaxf(v, __shfl_xor(v, 2));
      v = fmaxf(v, __shfl_xor(v, 4));
      v = fmaxf(v, __shfl_xor(v, 8));
      tm[rg] = v;
    }
    bool nomax = true;
#pragma unroll
    for (int rg = 0; rg < 4; ++rg) nomax = nomax && (tm[rg] <= mrow[rg] + 8.f);
    if (__all(nomax)) {
      // deferred path: keep stale max (p bounded by 2^8), no O-rescale
#pragma unroll
      for (int rg = 0; rg < 4; ++rg) {
        float rs = 0.f;
#pragma unroll
        for (int nt = 0; nt < 4; ++nt) {
          float p = exp2f(sacc[nt][rg] - mrow[rg]);
          sacc[nt][rg] = p;
          rs += p;
        }
        rs += __shfl_xor(rs, 1);
        rs += __shfl_xor(rs, 2);
        rs += __shfl_xor(rs, 4);
        rs += __shfl_xor(rs, 8);
        lrow[rg] += rs;
      }
    } else {
#pragma unroll
      for (int rg = 0; rg < 4; ++rg) {
        float nm = fmaxf(mrow[rg], tm[rg]);
        float alpha = exp2f(mrow[rg] - nm);
        mrow[rg] = nm;
        float rs = 0.f;
#pragma unroll
        for (int nt = 0; nt < 4; ++nt) {
          float p = exp2f(sacc[nt][rg] - nm);
          sacc[nt][rg] = p;
          rs += p;
        }
        rs += __shfl_xor(rs, 1);
        rs += __shfl_xor(rs, 2);
        rs += __shfl_xor(rs, 4);
        rs += __shfl_xor(rs, 8);
        lrow[rg] = lrow[rg] * alpha + rs;
#pragma unroll
        for (int nt = 0; nt < 8; ++nt) oacc[nt][rg] *= alpha;
      }
    }
    // P -> LDS (wave-private rows, no barrier needed)
#pragma unroll
    for (int nt = 0; nt < 4; ++nt)
#pragma unroll
      for (int rg = 0; rg < 4; ++rg)
        Ps[(wave * 16 + quad * 4 + rg) * 72 + nt * 16 + m16] =
            (__bf16)sacc[nt][rg];
    // O += P V
#pragma unroll
    for (int kc2 = 0; kc2 < 2; ++kc2) {
      bf16x8 af = *(const bf16x8*)&Ps[(wave * 16 + m16) * 72 + kc2 * 32 + quad * 8];
#pragma unroll
      for (int nt = 0; nt < 8; ++nt) {
        bf16x8 bv = *(const bf16x8*)&Vt[(nt * 16 + m16) * 72 + kc2 * 32 + quad * 8];
        oacc[nt] = MFMA_BF16(af, bv, oacc[nt]);
      }
    }
  }
  // epilogue
#pragma unroll
  for (int nt = 0; nt < 8; ++nt)
#pragma unroll
    for (int rg = 0; rg < 4; ++rg) {
      int sg = i0 + wave * 16 + quad * 4 + rg;
      int d = nt * 16 + m16;
      float val = oacc[nt][rg] / lrow[rg];
      Og[((size_t)b * S + sg) * 2048 + h * 128 + d] = (__bf16)val;
    }
}

// ---------------------------------------------------------------------------
extern "C" void kernel_launch(void* const* d_in, const int* in_sizes, int n_in,
                              void* d_out, int out_size, void* d_ws, size_t ws_size,
                              hipStream_t stream) {
  char* w0 = (char*)d_ws;
  int* flag = (int*)w0;
  char* w = w0 + 256;
  __bf16* hid_bf = (__bf16*)w;   w += (size_t)4096 * 5120 * 2;
  // wqa_bf and wkva_bf adjacent -> contiguous fused weight [2112][5120]
  __bf16* wqa_bf = (__bf16*)w;   w += (size_t)1536 * 5120 * 2;
  __bf16* wkva_bf = (__bf16*)w;  w += (size_t)576 * 5120 * 2;
  __bf16* wqb_bf = (__bf16*)w;   w += (size_t)3072 * 1536 * 2;
  __bf16* wkvb_bf = (__bf16*)w;  w += (size_t)4096 * 512 * 2;
  __bf16* wo_bf = (__bf16*)w;    w += (size_t)5120 * 2048 * 2;
  __bf16* cos_bf = (__bf16*)w;   w += (size_t)2048 * 64 * 2;
  __bf16* sin_bf = (__bf16*)w;   w += (size_t)2048 * 64 * 2;
  __bf16* qln_bf = (__bf16*)w;   w += 4096;
  __bf16* kvln_bf = (__bf16*)w;  w += 4096;
  float* qkv = (float*)w;        w += (size_t)4096 * 2112 * 4;  // [q_a(1536)|ckv(576)]
  __bf16* qan = (__bf16*)w;      w += (size_t)4096 * 1536 * 2;
  __bf16* qb = (__bf16*)w;       w += (size_t)4096 * 3072 * 2;
  __bf16* ckvn = (__bf16*)w;     w += (size_t)4096 * 512 * 2;
  __bf16* kvb = (__bf16*)w;      w += (size_t)4096 * 4096 * 2;
  // Overlays: Qg over hid_bf (dead after fused qkv_a gemm); Kg over
  // wqa_bf+wkva_bf+wqb_bf (all dead before prep_k); ao over qkv (dead after
  // rms + prep_k, attn writes it afterwards).
  __bf16* Qg = hid_bf;
  __bf16* Kg = wqa_bf;
  __bf16* ao = (__bf16*)qkv;

  sniff_k<<<1, 256, 0, stream>>>((const unsigned int*)d_in[0], flag);
  convert_k<<<1024, 256, 0, stream>>>(d_in[0], hid_bf, (long)4096 * 5120, flag);
  convert_k<<<1024, 256, 0, stream>>>(d_in[3], wqa_bf, (long)1536 * 5120, flag);
  convert_k<<<1024, 256, 0, stream>>>(d_in[5], wqb_bf, (long)3072 * 1536, flag);
  convert_k<<<1024, 256, 0, stream>>>(d_in[6], wkva_bf, (long)576 * 5120, flag);
  convert_k<<<1024, 256, 0, stream>>>(d_in[8], wkvb_bf, (long)4096 * 512, flag);
  convert_k<<<1024, 256, 0, stream>>>(d_in[9], wo_bf, (long)5120 * 2048, flag);
  convert_k<<<64, 256, 0, stream>>>(d_in[10], cos_bf, (long)2048 * 64, flag);
  convert_k<<<64, 256, 0, stream>>>(d_in[11], sin_bf, (long)2048 * 64, flag);
  convert_k<<<2, 256, 0, stream>>>(d_in[4], qln_bf, 1536, flag);
  convert_k<<<1, 256, 0, stream>>>(d_in[7], kvln_bf, 512, flag);

  // fused q_a + kv_a projection: [4096][2112] = hid @ [wq_a;wkv_a]^T
  gemm_bt<64, 0><<<dim3(33, 32), 256, 0, stream>>>(hid_bf, wqa_bf, qkv, flag, 4096, 2112, 5120, 5120, 5120, 2112);
  rms_k<1536><<<4096, 256, 0, stream>>>(qkv, 2112, qln_bf, qan, 1536);
  gemm_bt<128, 1><<<dim3(24, 32), 256, 0, stream>>>(qan, wqb_bf, qb, flag, 4096, 3072, 1536, 1536, 1536, 3072);
  rms_k<512><<<4096, 256, 0, stream>>>(qkv + 1536, 2112, kvln_bf, ckvn, 512);
  gemm_bt<128, 1><<<dim3(32, 32), 256, 0, stream>>>(ckvn, wkvb_bf, kvb, flag, 4096, 4096, 512, 512, 512, 4096);
  prep_k<<<4096, 192, 0, stream>>>(qb, qkv + 1536, kvb, cos_bf, sin_bf, Qg, Kg);
  attn_k<<<dim3(32, 32), 256, 0, stream>>>(Qg, Kg, kvb, ao);
  gemm_bt<128, 2><<<dim3(40, 32), 256, 0, stream>>>(ao, wo_bf, d_out, flag, 4096, 5120, 2048, 2048, 2048, 5120);
}